// Round 1
// baseline (308.587 us; speedup 1.0000x reference)
//
#include <hip/hip_runtime.h>
#include <stdint.h>

// Problem: B=8, C=64, H=W=64, N=4096.
// out[b,c,n] = x[b,c,n] + sum_j softmax_j(sum_k x[b,k,n]*x[b,k,j]) * support[b,j,c]
// support[b,j,c] = sum_k x[b,k,j] * W[k,c]
// => flash attention with Q=K=x^T [N,64], V=support [N,64].

#define NTOK 4096
#define CCH  64

typedef float v4f __attribute__((ext_vector_type(4)));
typedef __bf16 v8bf __attribute__((ext_vector_type(8)));
typedef unsigned short v8us __attribute__((ext_vector_type(8)));

__device__ __forceinline__ unsigned short f2bf(float f) {
    union { float f; unsigned int u; } c; c.f = f;
    unsigned int u = c.u;
    unsigned int r = u + 0x7fffu + ((u >> 16) & 1u);   // RNE
    return (unsigned short)(r >> 16);
}

__device__ __forceinline__ v8bf ld_bf8(const unsigned short* p) {
    union { v8us s; v8bf b; } u;
    u.s = *(const v8us*)p;
    return u.b;
}

// ---------------------------------------------------------------------------
// Prep: xT_bf16[b][n][c] = bf16(x[b][c][n]);  sT_bf16[b][d][n] = bf16(sum_c x[b][c][n] W[c][d])
// Grid: (16, 8) x 256 threads. Each thread owns one n.
// ---------------------------------------------------------------------------
__global__ __launch_bounds__(256) void prep_kernel(
    const float* __restrict__ x,        // [8][64][4096]
    const float* __restrict__ w,        // [64][64]
    unsigned short* __restrict__ xT,    // [8][4096][64] bf16
    unsigned short* __restrict__ sT)    // [8][64][4096] bf16
{
    __shared__ float Wl[64 * 64];
    const int tid = threadIdx.x;
    for (int i = tid; i < 64 * 64; i += 256) Wl[i] = w[i];
    __syncthreads();

    const int b = blockIdx.y;
    const int n = blockIdx.x * 256 + tid;
    const float* xb = x + (size_t)b * CCH * NTOK;

    float xr[64];
    #pragma unroll
    for (int c = 0; c < 64; ++c) xr[c] = xb[(size_t)c * NTOK + n];   // coalesced

    unsigned short* xtrow = xT + ((size_t)b * NTOK + n) * CCH;
    #pragma unroll
    for (int c = 0; c < 64; ++c) xtrow[c] = f2bf(xr[c]);

    unsigned short* stb = sT + (size_t)b * CCH * NTOK;
    for (int d = 0; d < 64; ++d) {
        float acc = 0.f;
        #pragma unroll
        for (int c = 0; c < 64; ++c) acc = fmaf(xr[c], Wl[c * 64 + d], acc);
        stb[(size_t)d * NTOK + n] = f2bf(acc);                       // coalesced
    }
}

// ---------------------------------------------------------------------------
// Flash attention. Grid: (64 i-tiles, 8 batches) x 256 threads (4 waves).
// Each wave owns 16 Q rows. K-tile = 64 columns.
// MFMA 16x16x32 bf16 layouts (verified, guide §3):
//   A: [m=lane&15][k=quad*8+j]   B: [k=quad*8+j][n=lane&15]   C/D: [row=quad*4+r][col=lane&15]
// ---------------------------------------------------------------------------
__global__ __launch_bounds__(256, 2) void flash_kernel(
    const unsigned short* __restrict__ xT,   // [8][4096][64]
    const unsigned short* __restrict__ sT,   // [8][64][4096]
    const float* __restrict__ x,             // [8][64][4096]
    float* __restrict__ out)                 // [8][64][4096]
{
    // P staging: per-wave 16x64 bf16, row stride 72 (16B-aligned, breaks bank pow2)
    __shared__ __align__(16) unsigned short Pl[4][16 * 72];
    __shared__ float Of[64 * 65];            // epilogue transpose, +1 pad

    const int tid  = threadIdx.x;
    const int w    = tid >> 6;
    const int lane = tid & 63;
    const int quad = lane >> 4;
    const int l16  = lane & 15;
    const int b    = blockIdx.y;
    const int i0   = blockIdx.x * 64;
    const int irow = i0 + 16 * w;

    const unsigned short* xTb = xT + (size_t)b * NTOK * CCH;
    const unsigned short* sTb = sT + (size_t)b * CCH * NTOK;

    // Q fragments (held for whole K loop)
    const v8bf aq0 = ld_bf8(xTb + (size_t)(irow + l16) * CCH + quad * 8);
    const v8bf aq1 = ld_bf8(xTb + (size_t)(irow + l16) * CCH + 32 + quad * 8);

    v4f o[4];
    #pragma unroll
    for (int ct = 0; ct < 4; ++ct) { o[ct][0]=0.f; o[ct][1]=0.f; o[ct][2]=0.f; o[ct][3]=0.f; }
    float m_i[4], l_i[4];
    #pragma unroll
    for (int r = 0; r < 4; ++r) { m_i[r] = -1e30f; l_i[r] = 0.f; }

    unsigned short* Pw = Pl[w];

    for (int j0 = 0; j0 < NTOK; j0 += 64) {
        // ---- S = Q K^T (16 x 64 per wave) ----
        v4f s[4];
        #pragma unroll
        for (int jt = 0; jt < 4; ++jt) {
            const unsigned short* kr = xTb + (size_t)(j0 + 16 * jt + l16) * CCH + quad * 8;
            v8bf bk0 = ld_bf8(kr);
            v8bf bk1 = ld_bf8(kr + 32);
            v4f z; z[0]=0.f; z[1]=0.f; z[2]=0.f; z[3]=0.f;
            z     = __builtin_amdgcn_mfma_f32_16x16x32_bf16(aq0, bk0, z, 0, 0, 0);
            s[jt] = __builtin_amdgcn_mfma_f32_16x16x32_bf16(aq1, bk1, z, 0, 0, 0);
        }

        // ---- online softmax (rows live on quad*4+r across 16 lanes x 4 jt) ----
        float rmax[4];
        #pragma unroll
        for (int r = 0; r < 4; ++r) {
            float t = fmaxf(fmaxf(s[0][r], s[1][r]), fmaxf(s[2][r], s[3][r]));
            t = fmaxf(t, __shfl_xor(t, 1));
            t = fmaxf(t, __shfl_xor(t, 2));
            t = fmaxf(t, __shfl_xor(t, 4));
            t = fmaxf(t, __shfl_xor(t, 8));
            rmax[r] = t;
        }
        float alpha[4], rsum[4];
        #pragma unroll
        for (int r = 0; r < 4; ++r) {
            float mnew = fmaxf(m_i[r], rmax[r]);
            alpha[r]   = __expf(m_i[r] - mnew);
            m_i[r]     = mnew;
            rsum[r]    = 0.f;
        }
        #pragma unroll
        for (int jt = 0; jt < 4; ++jt) {
            #pragma unroll
            for (int r = 0; r < 4; ++r) {
                float p = __expf(s[jt][r] - m_i[r]);
                rsum[r] += p;
                Pw[(quad * 4 + r) * 72 + 16 * jt + l16] = f2bf(p);
            }
        }
        #pragma unroll
        for (int r = 0; r < 4; ++r) {
            float t = rsum[r];
            t += __shfl_xor(t, 1);
            t += __shfl_xor(t, 2);
            t += __shfl_xor(t, 4);
            t += __shfl_xor(t, 8);
            l_i[r] = l_i[r] * alpha[r] + t;
        }
        #pragma unroll
        for (int ct = 0; ct < 4; ++ct) {
            #pragma unroll
            for (int r = 0; r < 4; ++r) o[ct][r] *= alpha[r];
        }

        // ---- P back out of LDS in A-layout (wave-local; no barrier needed) ----
        v8bf ap0 = ld_bf8(Pw + l16 * 72 + quad * 8);
        v8bf ap1 = ld_bf8(Pw + l16 * 72 + 32 + quad * 8);

        // ---- O += P V ----
        #pragma unroll
        for (int ct = 0; ct < 4; ++ct) {
            const unsigned short* vr = sTb + (size_t)(16 * ct + l16) * NTOK + j0 + quad * 8;
            v8bf bv0 = ld_bf8(vr);
            v8bf bv1 = ld_bf8(vr + 32);
            o[ct] = __builtin_amdgcn_mfma_f32_16x16x32_bf16(ap0, bv0, o[ct], 0, 0, 0);
            o[ct] = __builtin_amdgcn_mfma_f32_16x16x32_bf16(ap1, bv1, o[ct], 0, 0, 0);
        }
    }

    // ---- epilogue: normalize, transpose through LDS, add x, store ----
    #pragma unroll
    for (int r = 0; r < 4; ++r) {
        const float inv = 1.f / l_i[r];
        const int row = 16 * w + quad * 4 + r;     // local n in [0,64)
        #pragma unroll
        for (int ct = 0; ct < 4; ++ct)
            Of[row * 65 + 16 * ct + l16] = o[ct][r] * inv;
    }
    __syncthreads();

    const int c    = tid >> 2;        // 0..63
    const int part = tid & 3;         // 0..3 -> 16 n each
    const float* xrow = x   + ((size_t)b * CCH + c) * NTOK + i0 + part * 16;
    float*       orow = out + ((size_t)b * CCH + c) * NTOK + i0 + part * 16;
    #pragma unroll
    for (int i4 = 0; i4 < 4; ++i4) {
        float4 xv = *(const float4*)(xrow + i4 * 4);
        float4 ov;
        ov.x = Of[(part * 16 + i4 * 4 + 0) * 65 + c] + xv.x;
        ov.y = Of[(part * 16 + i4 * 4 + 1) * 65 + c] + xv.y;
        ov.z = Of[(part * 16 + i4 * 4 + 2) * 65 + c] + xv.z;
        ov.w = Of[(part * 16 + i4 * 4 + 3) * 65 + c] + xv.w;
        *(float4*)(orow + i4 * 4) = ov;
    }
}

// ---------------------------------------------------------------------------
extern "C" void kernel_launch(void* const* d_in, const int* in_sizes, int n_in,
                              void* d_out, int out_size, void* d_ws, size_t ws_size,
                              hipStream_t stream) {
    const float* x = (const float*)d_in[0];     // [8][64][4096] f32
    const float* w = (const float*)d_in[1];     // [64][64] f32
    float* out = (float*)d_out;                 // [8][64][4096] f32

    unsigned short* xT = (unsigned short*)d_ws;                 // 4 MB
    unsigned short* sT = xT + (size_t)8 * NTOK * CCH;           // 4 MB

    dim3 gp(16, 8);
    prep_kernel<<<gp, 256, 0, stream>>>(x, w, xT, sT);
    dim3 gf(64, 8);
    flash_kernel<<<gf, 256, 0, stream>>>(xT, sT, x, out);
}